// Round 1
// baseline (2647.338 us; speedup 1.0000x reference)
//
#include <hip/hip_runtime.h>

#define N_USERS 100000
#define N_ITEMS 50000
#define N_NODES 150000
#define HH 64
#define NEDGES 1200000
#define NQ 16384
#define LN_EPS 1e-5f

// ---------------------------------------------------------------------------
// Generic fused linear: Y[M,64] = act(X @ W.T + b), X = [X1 | X2] (K = K1+K2)
// act = ReLU -> LayerNorm(g,be) if RELULN, else identity.
// Tile: 64 rows x 64 cols, block 256 threads, 4x4 register tile per thread.
// ---------------------------------------------------------------------------
template<int K, int K1, bool RELULN>
__global__ __launch_bounds__(256)
void linear_kernel(const float* __restrict__ X1, const float* __restrict__ X2,
                   const float* __restrict__ W, const float* __restrict__ bias,
                   const float* __restrict__ g, const float* __restrict__ be,
                   float* __restrict__ Y, float* __restrict__ Y2,
                   int M, int yrow_off)
{
    constexpr int SA = K + 1;   // A stride: banks (r+k)%32 -> conflict-free
    constexpr int SW = 65;      // Wt stride: banks (k+n)%32 -> <=2-way
    __shared__ float As[64 * SA];
    __shared__ float Ws[K * SW];

    const int t = threadIdx.x;
    const int row0 = blockIdx.x * 64;

    // ---- stage A tile (coalesced global reads) ----
    constexpr int AIT = 64 * K / 256;
#pragma unroll
    for (int i = 0; i < AIT; ++i) {
        int e = t + i * 256;
        int r = e / K, k = e % K;
        int gr = row0 + r;
        float v = 0.f;
        if (gr < M) {
            if (K1 == K) v = X1[gr * K + k];
            else         v = (k < K1) ? X1[gr * K1 + k]
                                      : X2[gr * (K - K1) + (k - K1)];
        }
        As[r * SA + k] = v;
    }
    // ---- stage W transposed: Ws[k][n] ----
    constexpr int WIT = 64 * K / 256;
#pragma unroll
    for (int i = 0; i < WIT; ++i) {
        int e = t + i * 256;
        int n = e / K, k = e % K;
        Ws[k * SW + n] = W[e];
    }
    __syncthreads();

    const int r0 = 4 * (t / 16);
    const int n0 = 4 * (t & 15);
    float acc[4][4] = {};
#pragma unroll 8
    for (int k = 0; k < K; ++k) {
        float a0 = As[(r0 + 0) * SA + k];
        float a1 = As[(r0 + 1) * SA + k];
        float a2 = As[(r0 + 2) * SA + k];
        float a3 = As[(r0 + 3) * SA + k];
        float w0 = Ws[k * SW + n0 + 0];
        float w1 = Ws[k * SW + n0 + 1];
        float w2 = Ws[k * SW + n0 + 2];
        float w3 = Ws[k * SW + n0 + 3];
        acc[0][0] += a0 * w0; acc[0][1] += a0 * w1; acc[0][2] += a0 * w2; acc[0][3] += a0 * w3;
        acc[1][0] += a1 * w0; acc[1][1] += a1 * w1; acc[1][2] += a1 * w2; acc[1][3] += a1 * w3;
        acc[2][0] += a2 * w0; acc[2][1] += a2 * w1; acc[2][2] += a2 * w2; acc[2][3] += a2 * w3;
        acc[3][0] += a3 * w0; acc[3][1] += a3 * w1; acc[3][2] += a3 * w2; acc[3][3] += a3 * w3;
    }

    float bv[4] = { bias[n0], bias[n0 + 1], bias[n0 + 2], bias[n0 + 3] };
    float y[4][4];
#pragma unroll
    for (int j = 0; j < 4; ++j)
#pragma unroll
        for (int i = 0; i < 4; ++i) {
            float v = acc[j][i] + bv[i];
            if (RELULN) v = fmaxf(v, 0.f);
            y[j][i] = v;
        }

    if (RELULN) {
        float gv[4]  = { g[n0],  g[n0 + 1],  g[n0 + 2],  g[n0 + 3]  };
        float bev[4] = { be[n0], be[n0 + 1], be[n0 + 2], be[n0 + 3] };
#pragma unroll
        for (int j = 0; j < 4; ++j) {
            float s = y[j][0] + y[j][1] + y[j][2] + y[j][3];
            s += __shfl_xor(s, 1); s += __shfl_xor(s, 2);
            s += __shfl_xor(s, 4); s += __shfl_xor(s, 8);
            float mean = s * (1.f / 64.f);
            float d0 = y[j][0] - mean, d1 = y[j][1] - mean;
            float d2 = y[j][2] - mean, d3 = y[j][3] - mean;
            float q = d0 * d0 + d1 * d1 + d2 * d2 + d3 * d3;
            q += __shfl_xor(q, 1); q += __shfl_xor(q, 2);
            q += __shfl_xor(q, 4); q += __shfl_xor(q, 8);
            float inv = rsqrtf(q * (1.f / 64.f) + LN_EPS);
#pragma unroll
            for (int i = 0; i < 4; ++i)
                y[j][i] = (y[j][i] - mean) * inv * gv[i] + bev[i];
        }
    }

#pragma unroll
    for (int j = 0; j < 4; ++j) {
        int gr = row0 + r0 + j;
        if (gr < M) {
            float4 v = make_float4(y[j][0], y[j][1], y[j][2], y[j][3]);
            *reinterpret_cast<float4*>(&Y[(size_t)(yrow_off + gr) * HH + n0]) = v;
            if (Y2)
                *reinterpret_cast<float4*>(&Y2[(size_t)(yrow_off + gr) * HH + n0]) = v;
        }
    }
}

// ---------------------------------------------------------------------------
// SPMM: Xout[rows[e]] += vals[e] * Xin[cols[e]]  (atomic scatter)
// 16 threads per edge, float4 gather, 4 atomics each.
// ---------------------------------------------------------------------------
__global__ __launch_bounds__(256)
void spmm_atomic(const int* __restrict__ rows, const int* __restrict__ cols,
                 const float* __restrict__ vals, const float* __restrict__ Xin,
                 float* __restrict__ Xout)
{
    int idx = blockIdx.x * 256 + threadIdx.x;
    if (idx >= NEDGES * 16) return;
    int e = idx >> 4, q = idx & 15;
    int r = rows[e], c = cols[e];
    float v = vals[e];
    float4 x = *reinterpret_cast<const float4*>(&Xin[(size_t)c * HH + q * 4]);
    float* o = &Xout[(size_t)r * HH + q * 4];
    atomicAdd(o + 0, v * x.x);
    atomicAdd(o + 1, v * x.y);
    atomicAdd(o + 2, v * x.z);
    atomicAdd(o + 3, v * x.w);
}

__global__ __launch_bounds__(256)
void zero_kernel(float4* __restrict__ p, int n4)
{
    for (int i = blockIdx.x * 256 + threadIdx.x; i < n4; i += gridDim.x * 256)
        p[i] = make_float4(0.f, 0.f, 0.f, 0.f);
}

// A = relu(A) (optional, written back), z += A
__global__ __launch_bounds__(256)
void post_kernel(float4* __restrict__ A, float4* __restrict__ z, int n4, int dorelu)
{
    for (int i = blockIdx.x * 256 + threadIdx.x; i < n4; i += gridDim.x * 256) {
        float4 a = A[i];
        if (dorelu) {
            a.x = fmaxf(a.x, 0.f); a.y = fmaxf(a.y, 0.f);
            a.z = fmaxf(a.z, 0.f); a.w = fmaxf(a.w, 0.f);
            A[i] = a;
        }
        float4 zz = z[i];
        zz.x += a.x; zz.y += a.y; zz.z += a.z; zz.w += a.w;
        z[i] = zz;
    }
}

// ---------------------------------------------------------------------------
// Scorer: per query build pair[256] = [zu, zi, zu*zi, |zu-zi|] (z = acc/3),
// hidden = relu(pair @ s1W.T + s1b), score = hidden @ s2W + s2b,
// pred = clip(gm + ub + ib + score, 1, 5).  64 queries per block.
// ---------------------------------------------------------------------------
__global__ __launch_bounds__(256)
void scorer_kernel(const float* __restrict__ z, const int* __restrict__ uidx,
                   const int* __restrict__ iidx,
                   const float* __restrict__ s1W, const float* __restrict__ s1b,
                   const float* __restrict__ s2W, const float* __restrict__ s2b,
                   const float* __restrict__ ubias, const float* __restrict__ ibias,
                   const float* __restrict__ gmean, float* __restrict__ out)
{
    constexpr int SA = 261, SW = 65;
    __shared__ float As[64 * SA];   // 66.8 KB
    __shared__ float Ws[256 * SW];  // 66.6 KB

    const int t = threadIdx.x;
    const int row0 = blockIdx.x * 64;

    // load zu | zi (scaled by 1/3)
#pragma unroll
    for (int i = 0; i < 32; ++i) {
        int e = t + i * 256;
        int half = e >> 12;
        int idx = e & 4095;
        int r = idx >> 6, c = idx & 63;
        int q = row0 + r;
        int node = half ? (N_USERS + iidx[q]) : uidx[q];
        As[r * SA + half * 64 + c] = z[(size_t)node * HH + c] * (1.f / 3.f);
    }
    // stage s1W transposed
#pragma unroll
    for (int i = 0; i < 64; ++i) {
        int e = t + i * 256;
        int n = e >> 8, k = e & 255;
        Ws[k * SW + n] = s1W[e];
    }
    __syncthreads();
    // products
#pragma unroll
    for (int i = 0; i < 16; ++i) {
        int e = t + i * 256;
        int r = e >> 6, c = e & 63;
        float a = As[r * SA + c], b = As[r * SA + 64 + c];
        As[r * SA + 128 + c] = a * b;
        As[r * SA + 192 + c] = fabsf(a - b);
    }
    __syncthreads();

    const int r0 = 4 * (t / 16);
    const int n0 = 4 * (t & 15);
    float acc[4][4] = {};
#pragma unroll 8
    for (int k = 0; k < 256; ++k) {
        float a0 = As[(r0 + 0) * SA + k];
        float a1 = As[(r0 + 1) * SA + k];
        float a2 = As[(r0 + 2) * SA + k];
        float a3 = As[(r0 + 3) * SA + k];
        float w0 = Ws[k * SW + n0 + 0];
        float w1 = Ws[k * SW + n0 + 1];
        float w2 = Ws[k * SW + n0 + 2];
        float w3 = Ws[k * SW + n0 + 3];
        acc[0][0] += a0 * w0; acc[0][1] += a0 * w1; acc[0][2] += a0 * w2; acc[0][3] += a0 * w3;
        acc[1][0] += a1 * w0; acc[1][1] += a1 * w1; acc[1][2] += a1 * w2; acc[1][3] += a1 * w3;
        acc[2][0] += a2 * w0; acc[2][1] += a2 * w1; acc[2][2] += a2 * w2; acc[2][3] += a2 * w3;
        acc[3][0] += a3 * w0; acc[3][1] += a3 * w1; acc[3][2] += a3 * w2; acc[3][3] += a3 * w3;
    }

    float b1[4]  = { s1b[n0], s1b[n0 + 1], s1b[n0 + 2], s1b[n0 + 3] };
    float s2w[4] = { s2W[n0], s2W[n0 + 1], s2W[n0 + 2], s2W[n0 + 3] };
    float pj[4];
#pragma unroll
    for (int j = 0; j < 4; ++j) {
        float p = 0.f;
#pragma unroll
        for (int i = 0; i < 4; ++i)
            p += fmaxf(acc[j][i] + b1[i], 0.f) * s2w[i];
        p += __shfl_xor(p, 1); p += __shfl_xor(p, 2);
        p += __shfl_xor(p, 4); p += __shfl_xor(p, 8);
        pj[j] = p;
    }
    if ((t & 15) == 0) {
        float gm = gmean[0], b2 = s2b[0];
#pragma unroll
        for (int j = 0; j < 4; ++j) {
            int q = row0 + r0 + j;
            float pred = gm + ubias[uidx[q]] + ibias[iidx[q]] + b2 + pj[j];
            pred = fminf(fmaxf(pred, 1.f), 5.f);
            out[q] = pred;
        }
    }
}

// ---------------------------------------------------------------------------
extern "C" void kernel_launch(void* const* d_in, const int* in_sizes, int n_in,
                              void* d_out, int out_size, void* d_ws, size_t ws_size,
                              hipStream_t stream)
{
    const float* user_feat = (const float*)d_in[0];
    const float* item_feat = (const float*)d_in[1];
    const float* adj_vals  = (const float*)d_in[2];
    const float* ue_W  = (const float*)d_in[3];
    const float* ue_b  = (const float*)d_in[4];
    const float* ue_g  = (const float*)d_in[5];
    const float* ue_be = (const float*)d_in[6];
    const float* ie_W  = (const float*)d_in[7];
    const float* ie_b  = (const float*)d_in[8];
    const float* ie_g  = (const float*)d_in[9];
    const float* ie_be = (const float*)d_in[10];
    const float* uid_emb = (const float*)d_in[11];
    const float* iid_emb = (const float*)d_in[12];
    const float* uf_W  = (const float*)d_in[13];
    const float* uf_b  = (const float*)d_in[14];
    const float* uf_g  = (const float*)d_in[15];
    const float* uf_be = (const float*)d_in[16];
    const float* if_W  = (const float*)d_in[17];
    const float* if_b  = (const float*)d_in[18];
    const float* if_g  = (const float*)d_in[19];
    const float* if_be = (const float*)d_in[20];
    const float* gcn_W = (const float*)d_in[21];
    const float* gcn_b = (const float*)d_in[22];
    const float* ubias = (const float*)d_in[23];
    const float* ibias = (const float*)d_in[24];
    const float* s1_W  = (const float*)d_in[25];
    const float* s1_b  = (const float*)d_in[26];
    const float* s2_W  = (const float*)d_in[27];
    const float* s2_b  = (const float*)d_in[28];
    const float* gmean = (const float*)d_in[29];
    const int* adj_rows = (const int*)d_in[30];
    const int* adj_cols = (const int*)d_in[31];
    const int* user_idx = (const int*)d_in[32];
    const int* item_idx = (const int*)d_in[33];
    float* out = (float*)d_out;

    float* z = (float*)d_ws;               // [150000*64]
    float* A = z + (size_t)N_NODES * HH;   // [150000*64]
    float* B = A + (size_t)N_NODES * HH;   // [150000*64]

    const int n4 = N_NODES * HH / 4;
    const int ublocks = (N_USERS + 63) / 64;   // 1563
    const int iblocks = (N_ITEMS + 63) / 64;   // 782
    const int nblocks = (N_NODES + 63) / 64;   // 2344

    // ---- encode: feature encoders -> B (tmp) ----
    linear_kernel<128, 128, true><<<ublocks, 256, 0, stream>>>(
        user_feat, nullptr, ue_W, ue_b, ue_g, ue_be, B, nullptr, N_USERS, 0);
    linear_kernel<128, 128, true><<<iblocks, 256, 0, stream>>>(
        item_feat, nullptr, ie_W, ie_b, ie_g, ie_be, B, nullptr, N_ITEMS, N_USERS);
    // ---- fusion: [feat | id_emb] -> z (=x0=acc) and A (=x) ----
    linear_kernel<128, 64, true><<<ublocks, 256, 0, stream>>>(
        B, uid_emb, uf_W, uf_b, uf_g, uf_be, z, A, N_USERS, 0);
    linear_kernel<128, 64, true><<<iblocks, 256, 0, stream>>>(
        B + (size_t)N_USERS * HH, iid_emb, if_W, if_b, if_g, if_be, z, A, N_ITEMS, N_USERS);

    // ---- GCN layers ----
    for (int l = 0; l < 2; ++l) {
        linear_kernel<64, 64, false><<<nblocks, 256, 0, stream>>>(
            A, nullptr, gcn_W + l * HH * HH, gcn_b + l * HH,
            nullptr, nullptr, B, nullptr, N_NODES, 0);
        zero_kernel<<<2048, 256, 0, stream>>>((float4*)A, n4);
        spmm_atomic<<<NEDGES * 16 / 256, 256, 0, stream>>>(adj_rows, adj_cols, adj_vals, B, A);
        post_kernel<<<2048, 256, 0, stream>>>((float4*)A, (float4*)z, n4, l == 0 ? 1 : 0);
    }

    // ---- scorer ----
    scorer_kernel<<<NQ / 64, 256, 0, stream>>>(
        z, user_idx, item_idx, s1_W, s1_b, s2_W, s2_b, ubias, ibias, gmean, out);
}

// Round 3
// 802.253 us; speedup vs baseline: 3.2999x; 3.2999x over previous
//
#include <hip/hip_runtime.h>

#define N_USERS 100000
#define N_ITEMS 50000
#define N_NODES 150000
#define HH 64
#define NEDGES 1200000
#define NQ 16384
#define LN_EPS 1e-5f
#define SCAN_NBLK 147   // ceil(150000/1024)

// ---------------------------------------------------------------------------
// Generic fused linear: Y[M,64] = act(X @ W.T + b), X = [X1 | X2] (K = K1+K2)
// ---------------------------------------------------------------------------
template<int K, int K1, bool RELULN>
__global__ __launch_bounds__(256)
void linear_kernel(const float* __restrict__ X1, const float* __restrict__ X2,
                   const float* __restrict__ W, const float* __restrict__ bias,
                   const float* __restrict__ g, const float* __restrict__ be,
                   float* __restrict__ Y, float* __restrict__ Y2,
                   int M, int yrow_off)
{
    constexpr int SA = K + 1;
    constexpr int SW = 65;
    __shared__ float As[64 * SA];
    __shared__ float Ws[K * SW];

    const int t = threadIdx.x;
    const int row0 = blockIdx.x * 64;

    constexpr int AIT = 64 * K / 256;
#pragma unroll
    for (int i = 0; i < AIT; ++i) {
        int e = t + i * 256;
        int r = e / K, k = e % K;
        int gr = row0 + r;
        float v = 0.f;
        if (gr < M) {
            if (K1 == K) v = X1[gr * K + k];
            else         v = (k < K1) ? X1[gr * K1 + k]
                                      : X2[gr * (K - K1) + (k - K1)];
        }
        As[r * SA + k] = v;
    }
    constexpr int WIT = 64 * K / 256;
#pragma unroll
    for (int i = 0; i < WIT; ++i) {
        int e = t + i * 256;
        int n = e / K, k = e % K;
        Ws[k * SW + n] = W[e];
    }
    __syncthreads();

    const int r0 = 4 * (t / 16);
    const int n0 = 4 * (t & 15);
    float acc[4][4] = {};
#pragma unroll 8
    for (int k = 0; k < K; ++k) {
        float a0 = As[(r0 + 0) * SA + k];
        float a1 = As[(r0 + 1) * SA + k];
        float a2 = As[(r0 + 2) * SA + k];
        float a3 = As[(r0 + 3) * SA + k];
        float w0 = Ws[k * SW + n0 + 0];
        float w1 = Ws[k * SW + n0 + 1];
        float w2 = Ws[k * SW + n0 + 2];
        float w3 = Ws[k * SW + n0 + 3];
        acc[0][0] += a0 * w0; acc[0][1] += a0 * w1; acc[0][2] += a0 * w2; acc[0][3] += a0 * w3;
        acc[1][0] += a1 * w0; acc[1][1] += a1 * w1; acc[1][2] += a1 * w2; acc[1][3] += a1 * w3;
        acc[2][0] += a2 * w0; acc[2][1] += a2 * w1; acc[2][2] += a2 * w2; acc[2][3] += a2 * w3;
        acc[3][0] += a3 * w0; acc[3][1] += a3 * w1; acc[3][2] += a3 * w2; acc[3][3] += a3 * w3;
    }

    float bv[4] = { bias[n0], bias[n0 + 1], bias[n0 + 2], bias[n0 + 3] };
    float y[4][4];
#pragma unroll
    for (int j = 0; j < 4; ++j)
#pragma unroll
        for (int i = 0; i < 4; ++i) {
            float v = acc[j][i] + bv[i];
            if (RELULN) v = fmaxf(v, 0.f);
            y[j][i] = v;
        }

    if (RELULN) {
        float gv[4]  = { g[n0],  g[n0 + 1],  g[n0 + 2],  g[n0 + 3]  };
        float bev[4] = { be[n0], be[n0 + 1], be[n0 + 2], be[n0 + 3] };
#pragma unroll
        for (int j = 0; j < 4; ++j) {
            float s = y[j][0] + y[j][1] + y[j][2] + y[j][3];
            s += __shfl_xor(s, 1); s += __shfl_xor(s, 2);
            s += __shfl_xor(s, 4); s += __shfl_xor(s, 8);
            float mean = s * (1.f / 64.f);
            float d0 = y[j][0] - mean, d1 = y[j][1] - mean;
            float d2 = y[j][2] - mean, d3 = y[j][3] - mean;
            float q = d0 * d0 + d1 * d1 + d2 * d2 + d3 * d3;
            q += __shfl_xor(q, 1); q += __shfl_xor(q, 2);
            q += __shfl_xor(q, 4); q += __shfl_xor(q, 8);
            float inv = rsqrtf(q * (1.f / 64.f) + LN_EPS);
#pragma unroll
            for (int i = 0; i < 4; ++i)
                y[j][i] = (y[j][i] - mean) * inv * gv[i] + bev[i];
        }
    }

#pragma unroll
    for (int j = 0; j < 4; ++j) {
        int gr = row0 + r0 + j;
        if (gr < M) {
            float4 v = make_float4(y[j][0], y[j][1], y[j][2], y[j][3]);
            *reinterpret_cast<float4*>(&Y[(size_t)(yrow_off + gr) * HH + n0]) = v;
            if (Y2)
                *reinterpret_cast<float4*>(&Y2[(size_t)(yrow_off + gr) * HH + n0]) = v;
        }
    }
}

// ---------------------------------------------------------------------------
// CSR build
// ---------------------------------------------------------------------------
__global__ __launch_bounds__(256)
void zero_int_kernel(int* __restrict__ p, int n)
{
    for (int i = blockIdx.x * 256 + threadIdx.x; i < n; i += gridDim.x * 256)
        p[i] = 0;
}

__global__ __launch_bounds__(256)
void hist_kernel(const int* __restrict__ rows, int* __restrict__ counts)
{
    int e = blockIdx.x * 256 + threadIdx.x;
    if (e < NEDGES) atomicAdd(&counts[rows[e]], 1);
}

// per-block exclusive scan of 1024 elements (256 thr x 4), emits block sums
__global__ __launch_bounds__(256)
void scan_blocks_kernel(const int* __restrict__ counts, int* __restrict__ ex,
                        int* __restrict__ bsum)
{
    __shared__ int wtot[4];
    int t = threadIdx.x;
    int base = blockIdx.x * 1024 + t * 4;
    int v0 = 0, v1 = 0, v2 = 0, v3 = 0;
    if (base + 3 < N_NODES) {
        int4 c = *reinterpret_cast<const int4*>(&counts[base]);
        v0 = c.x; v1 = c.y; v2 = c.z; v3 = c.w;
    } else {
        if (base + 0 < N_NODES) v0 = counts[base + 0];
        if (base + 1 < N_NODES) v1 = counts[base + 1];
        if (base + 2 < N_NODES) v2 = counts[base + 2];
        if (base + 3 < N_NODES) v3 = counts[base + 3];
    }
    int s1 = v0 + v1, s2 = s1 + v2, tot = s2 + v3;
    int inc = tot;
#pragma unroll
    for (int d = 1; d < 64; d <<= 1) {
        int u = __shfl_up(inc, d);
        if ((t & 63) >= d) inc += u;
    }
    if ((t & 63) == 63) wtot[t >> 6] = inc;
    __syncthreads();
    int w = t >> 6;
    int woff = 0;
#pragma unroll
    for (int i = 0; i < 4; ++i)
        if (i < w) woff += wtot[i];
    int ex0 = woff + inc - tot;
    if (base + 0 < N_NODES) ex[base + 0] = ex0;
    if (base + 1 < N_NODES) ex[base + 1] = ex0 + v0;
    if (base + 2 < N_NODES) ex[base + 2] = ex0 + s1;
    if (base + 3 < N_NODES) ex[base + 3] = ex0 + s2;
    if (t == 255) bsum[blockIdx.x] = woff + inc;
}

// exclusive scan of the (<=256) block sums, in place
__global__ __launch_bounds__(256)
void scan_small_kernel(int* __restrict__ bsum, int nb)
{
    __shared__ int wtot[4];
    int t = threadIdx.x;
    int v = (t < nb) ? bsum[t] : 0;
    int inc = v;
#pragma unroll
    for (int d = 1; d < 64; d <<= 1) {
        int u = __shfl_up(inc, d);
        if ((t & 63) >= d) inc += u;
    }
    if ((t & 63) == 63) wtot[t >> 6] = inc;
    __syncthreads();
    int w = t >> 6;
    int woff = 0;
#pragma unroll
    for (int i = 0; i < 4; ++i)
        if (i < w) woff += wtot[i];
    if (t < nb) bsum[t] = woff + inc - v;
}

__global__ __launch_bounds__(256)
void finalize_kernel(int* __restrict__ row_ptr, const int* __restrict__ bsum,
                     int* __restrict__ cursor)
{
    int i = blockIdx.x * 256 + threadIdx.x;
    if (i < N_NODES) {
        int v = row_ptr[i] + bsum[i >> 10];
        row_ptr[i] = v;
        cursor[i] = v;
    }
    if (i == 0) row_ptr[N_NODES] = NEDGES;
}

__global__ __launch_bounds__(256)
void scatter_kernel(const int* __restrict__ rows, const int* __restrict__ cols,
                    const float* __restrict__ vals, int* __restrict__ cursor,
                    int* __restrict__ csr_col, float* __restrict__ csr_val)
{
    int e = blockIdx.x * 256 + threadIdx.x;
    if (e < NEDGES) {
        int r = rows[e];
        int p = atomicAdd(&cursor[r], 1);
        csr_col[p] = cols[e];
        csr_val[p] = vals[e];
    }
}

// ---------------------------------------------------------------------------
// CSR SPMM: 16 lanes per row (float4 over H=64), fused relu + z-accumulate.
//   x = spmm(B); if(relu) x=relu(x); if(writeA) A=x; z += x;
// Edge loop unrolled x2: two independent gather chains in flight.
// ---------------------------------------------------------------------------
__global__ __launch_bounds__(256)
void spmm_csr_kernel(const int* __restrict__ row_ptr, const int* __restrict__ csr_col,
                     const float* __restrict__ csr_val, const float* __restrict__ Xin,
                     float* __restrict__ A, float* __restrict__ z,
                     int dorelu, int writeA)
{
    int t = threadIdx.x;
    int r = blockIdx.x * 16 + (t >> 4);
    if (r >= N_NODES) return;
    int q = (t & 15) * 4;
    int e = row_ptr[r], end = row_ptr[r + 1];
    float4 acc = make_float4(0.f, 0.f, 0.f, 0.f);
    for (; e + 1 < end; e += 2) {
        int c0 = csr_col[e], c1 = csr_col[e + 1];
        float v0 = csr_val[e], v1 = csr_val[e + 1];
        float4 x0 = *reinterpret_cast<const float4*>(&Xin[(size_t)c0 * HH + q]);
        float4 x1 = *reinterpret_cast<const float4*>(&Xin[(size_t)c1 * HH + q]);
        acc.x += v0 * x0.x; acc.y += v0 * x0.y; acc.z += v0 * x0.z; acc.w += v0 * x0.w;
        acc.x += v1 * x1.x; acc.y += v1 * x1.y; acc.z += v1 * x1.z; acc.w += v1 * x1.w;
    }
    if (e < end) {
        int c = csr_col[e];
        float v = csr_val[e];
        float4 x = *reinterpret_cast<const float4*>(&Xin[(size_t)c * HH + q]);
        acc.x += v * x.x; acc.y += v * x.y; acc.z += v * x.z; acc.w += v * x.w;
    }
    if (dorelu) {
        acc.x = fmaxf(acc.x, 0.f); acc.y = fmaxf(acc.y, 0.f);
        acc.z = fmaxf(acc.z, 0.f); acc.w = fmaxf(acc.w, 0.f);
    }
    size_t o = (size_t)r * HH + q;
    if (writeA) *reinterpret_cast<float4*>(&A[o]) = acc;
    float4 zz = *reinterpret_cast<float4*>(&z[o]);
    zz.x += acc.x; zz.y += acc.y; zz.z += acc.z; zz.w += acc.w;
    *reinterpret_cast<float4*>(&z[o]) = zz;
}

// ---------------------------------------------------------------------------
// Scorer
// ---------------------------------------------------------------------------
__global__ __launch_bounds__(256)
void scorer_kernel(const float* __restrict__ z, const int* __restrict__ uidx,
                   const int* __restrict__ iidx,
                   const float* __restrict__ s1W, const float* __restrict__ s1b,
                   const float* __restrict__ s2W, const float* __restrict__ s2b,
                   const float* __restrict__ ubias, const float* __restrict__ ibias,
                   const float* __restrict__ gmean, float* __restrict__ out)
{
    constexpr int SA = 261, SW = 65;
    __shared__ float As[64 * SA];
    __shared__ float Ws[256 * SW];

    const int t = threadIdx.x;
    const int row0 = blockIdx.x * 64;

#pragma unroll
    for (int i = 0; i < 32; ++i) {
        int e = t + i * 256;
        int half = e >> 12;
        int idx = e & 4095;
        int r = idx >> 6, c = idx & 63;
        int q = row0 + r;
        int node = half ? (N_USERS + iidx[q]) : uidx[q];
        As[r * SA + half * 64 + c] = z[(size_t)node * HH + c] * (1.f / 3.f);
    }
#pragma unroll
    for (int i = 0; i < 64; ++i) {
        int e = t + i * 256;
        int n = e >> 8, k = e & 255;
        Ws[k * SW + n] = s1W[e];
    }
    __syncthreads();
#pragma unroll
    for (int i = 0; i < 16; ++i) {
        int e = t + i * 256;
        int r = e >> 6, c = e & 63;
        float a = As[r * SA + c], b = As[r * SA + 64 + c];
        As[r * SA + 128 + c] = a * b;
        As[r * SA + 192 + c] = fabsf(a - b);
    }
    __syncthreads();

    const int r0 = 4 * (t / 16);
    const int n0 = 4 * (t & 15);
    float acc[4][4] = {};
#pragma unroll 8
    for (int k = 0; k < 256; ++k) {
        float a0 = As[(r0 + 0) * SA + k];
        float a1 = As[(r0 + 1) * SA + k];
        float a2 = As[(r0 + 2) * SA + k];
        float a3 = As[(r0 + 3) * SA + k];
        float w0 = Ws[k * SW + n0 + 0];
        float w1 = Ws[k * SW + n0 + 1];
        float w2 = Ws[k * SW + n0 + 2];
        float w3 = Ws[k * SW + n0 + 3];
        acc[0][0] += a0 * w0; acc[0][1] += a0 * w1; acc[0][2] += a0 * w2; acc[0][3] += a0 * w3;
        acc[1][0] += a1 * w0; acc[1][1] += a1 * w1; acc[1][2] += a1 * w2; acc[1][3] += a1 * w3;
        acc[2][0] += a2 * w0; acc[2][1] += a2 * w1; acc[2][2] += a2 * w2; acc[2][3] += a2 * w3;
        acc[3][0] += a3 * w0; acc[3][1] += a3 * w1; acc[3][2] += a3 * w2; acc[3][3] += a3 * w3;
    }

    float b1[4]  = { s1b[n0], s1b[n0 + 1], s1b[n0 + 2], s1b[n0 + 3] };
    float s2w[4] = { s2W[n0], s2W[n0 + 1], s2W[n0 + 2], s2W[n0 + 3] };
    float pj[4];
#pragma unroll
    for (int j = 0; j < 4; ++j) {
        float p = 0.f;
#pragma unroll
        for (int i = 0; i < 4; ++i)
            p += fmaxf(acc[j][i] + b1[i], 0.f) * s2w[i];
        p += __shfl_xor(p, 1); p += __shfl_xor(p, 2);
        p += __shfl_xor(p, 4); p += __shfl_xor(p, 8);
        pj[j] = p;
    }
    if ((t & 15) == 0) {
        float gm = gmean[0], b2 = s2b[0];
#pragma unroll
        for (int j = 0; j < 4; ++j) {
            int q = row0 + r0 + j;
            float pred = gm + ubias[uidx[q]] + ibias[iidx[q]] + b2 + pj[j];
            pred = fminf(fmaxf(pred, 1.f), 5.f);
            out[q] = pred;
        }
    }
}

// ---------------------------------------------------------------------------
extern "C" void kernel_launch(void* const* d_in, const int* in_sizes, int n_in,
                              void* d_out, int out_size, void* d_ws, size_t ws_size,
                              hipStream_t stream)
{
    const float* user_feat = (const float*)d_in[0];
    const float* item_feat = (const float*)d_in[1];
    const float* adj_vals  = (const float*)d_in[2];
    const float* ue_W  = (const float*)d_in[3];
    const float* ue_b  = (const float*)d_in[4];
    const float* ue_g  = (const float*)d_in[5];
    const float* ue_be = (const float*)d_in[6];
    const float* ie_W  = (const float*)d_in[7];
    const float* ie_b  = (const float*)d_in[8];
    const float* ie_g  = (const float*)d_in[9];
    const float* ie_be = (const float*)d_in[10];
    const float* uid_emb = (const float*)d_in[11];
    const float* iid_emb = (const float*)d_in[12];
    const float* uf_W  = (const float*)d_in[13];
    const float* uf_b  = (const float*)d_in[14];
    const float* uf_g  = (const float*)d_in[15];
    const float* uf_be = (const float*)d_in[16];
    const float* if_W  = (const float*)d_in[17];
    const float* if_b  = (const float*)d_in[18];
    const float* if_g  = (const float*)d_in[19];
    const float* if_be = (const float*)d_in[20];
    const float* gcn_W = (const float*)d_in[21];
    const float* gcn_b = (const float*)d_in[22];
    const float* ubias = (const float*)d_in[23];
    const float* ibias = (const float*)d_in[24];
    const float* s1_W  = (const float*)d_in[25];
    const float* s1_b  = (const float*)d_in[26];
    const float* s2_W  = (const float*)d_in[27];
    const float* s2_b  = (const float*)d_in[28];
    const float* gmean = (const float*)d_in[29];
    const int* adj_rows = (const int*)d_in[30];
    const int* adj_cols = (const int*)d_in[31];
    const int* user_idx = (const int*)d_in[32];
    const int* item_idx = (const int*)d_in[33];
    float* out = (float*)d_out;

    // workspace carve-up (keep 16B alignment)
    float* z = (float*)d_ws;                       // [N*64]
    float* A = z + (size_t)N_NODES * HH;           // [N*64]
    float* B = A + (size_t)N_NODES * HH;           // [N*64]
    float* csr_val = B + (size_t)N_NODES * HH;     // [E]
    int* csr_col = (int*)(csr_val + NEDGES);       // [E]
    int* row_ptr = csr_col + NEDGES;               // [N+1]
    int* cursor  = row_ptr + N_NODES + 4;          // [N]
    int* bsum    = cursor + N_NODES;               // [SCAN_NBLK]

    const int ublocks = (N_USERS + 63) / 64;
    const int iblocks = (N_ITEMS + 63) / 64;
    const int nblocks = (N_NODES + 63) / 64;
    const int eblocks = (NEDGES + 255) / 256;

    // ---- CSR build (graph is identical for both layers) ----
    zero_int_kernel<<<512, 256, 0, stream>>>(cursor, N_NODES);
    hist_kernel<<<eblocks, 256, 0, stream>>>(adj_rows, cursor);
    scan_blocks_kernel<<<SCAN_NBLK, 256, 0, stream>>>(cursor, row_ptr, bsum);
    scan_small_kernel<<<1, 256, 0, stream>>>(bsum, SCAN_NBLK);
    finalize_kernel<<<(N_NODES + 255) / 256, 256, 0, stream>>>(row_ptr, bsum, cursor);
    scatter_kernel<<<eblocks, 256, 0, stream>>>(adj_rows, adj_cols, adj_vals,
                                                cursor, csr_col, csr_val);

    // ---- encode: feature encoders -> B (tmp) ----
    linear_kernel<128, 128, true><<<ublocks, 256, 0, stream>>>(
        user_feat, nullptr, ue_W, ue_b, ue_g, ue_be, B, nullptr, N_USERS, 0);
    linear_kernel<128, 128, true><<<iblocks, 256, 0, stream>>>(
        item_feat, nullptr, ie_W, ie_b, ie_g, ie_be, B, nullptr, N_ITEMS, N_USERS);
    // ---- fusion: [feat | id_emb] -> z (=x0=acc) and A (=x) ----
    linear_kernel<128, 64, true><<<ublocks, 256, 0, stream>>>(
        B, uid_emb, uf_W, uf_b, uf_g, uf_be, z, A, N_USERS, 0);
    linear_kernel<128, 64, true><<<iblocks, 256, 0, stream>>>(
        B + (size_t)N_USERS * HH, iid_emb, if_W, if_b, if_g, if_be, z, A, N_ITEMS, N_USERS);

    // ---- GCN layers: B = A@W.T+b ; x = csr_spmm(B) ; fused relu/acc ----
    const int sblocks = (N_NODES * 16 + 255) / 256;
    for (int l = 0; l < 2; ++l) {
        linear_kernel<64, 64, false><<<nblocks, 256, 0, stream>>>(
            A, nullptr, gcn_W + l * HH * HH, gcn_b + l * HH,
            nullptr, nullptr, B, nullptr, N_NODES, 0);
        spmm_csr_kernel<<<sblocks, 256, 0, stream>>>(
            row_ptr, csr_col, csr_val, B, A, z,
            /*dorelu=*/l == 0 ? 1 : 0, /*writeA=*/l == 0 ? 1 : 0);
    }

    // ---- scorer ----
    scorer_kernel<<<NQ / 64, 256, 0, stream>>>(
        z, user_idx, item_idx, s1_W, s1_b, s2_W, s2_b, ubias, ibias, gmean, out);
}

// Round 4
// 606.717 us; speedup vs baseline: 4.3634x; 1.3223x over previous
//
#include <hip/hip_runtime.h>

#define N_USERS 100000
#define N_ITEMS 50000
#define N_NODES 150000
#define HH 64
#define NEDGES 1200000
#define NQ 16384
#define LN_EPS 1e-5f
#define SCAN_NBLK 147   // ceil(150000/1024)

// ---------------------------------------------------------------------------
// Shared GEMM tile helpers: 64 rows x 64 cols, 256 threads, 4x4 per thread.
// All LDS reads are float4 (ds_read_b128). Strides keep conflicts <=2-way.
// ---------------------------------------------------------------------------
template<int K, int SA, int SW>
__device__ __forceinline__ void gemm_tile(const float* __restrict__ As,
                                          const float* __restrict__ Ws,
                                          int r0, int n0, float acc[4][4])
{
#pragma unroll 2
    for (int k0 = 0; k0 < K; k0 += 4) {
        float4 a[4], w[4];
        a[0] = *(const float4*)&As[(r0 + 0) * SA + k0];
        a[1] = *(const float4*)&As[(r0 + 1) * SA + k0];
        a[2] = *(const float4*)&As[(r0 + 2) * SA + k0];
        a[3] = *(const float4*)&As[(r0 + 3) * SA + k0];
        w[0] = *(const float4*)&Ws[(k0 + 0) * SW + n0];
        w[1] = *(const float4*)&Ws[(k0 + 1) * SW + n0];
        w[2] = *(const float4*)&Ws[(k0 + 2) * SW + n0];
        w[3] = *(const float4*)&Ws[(k0 + 3) * SW + n0];
#pragma unroll
        for (int j = 0; j < 4; ++j) {
            float av[4] = { a[j].x, a[j].y, a[j].z, a[j].w };
#pragma unroll
            for (int kk = 0; kk < 4; ++kk) {
                float wv[4] = { w[kk].x, w[kk].y, w[kk].z, w[kk].w };
                acc[j][0] += av[kk] * wv[0];
                acc[j][1] += av[kk] * wv[1];
                acc[j][2] += av[kk] * wv[2];
                acc[j][3] += av[kk] * wv[3];
            }
        }
    }
}

// bias+ReLU+LayerNorm epilogue (rows live in 16 contiguous lanes)
__device__ __forceinline__ void relu_ln(float acc[4][4], float y[4][4],
                                        const float* __restrict__ bias,
                                        const float* __restrict__ g,
                                        const float* __restrict__ be, int n0)
{
    float bv[4] = { bias[n0], bias[n0 + 1], bias[n0 + 2], bias[n0 + 3] };
    float gv[4] = { g[n0], g[n0 + 1], g[n0 + 2], g[n0 + 3] };
    float bev[4] = { be[n0], be[n0 + 1], be[n0 + 2], be[n0 + 3] };
#pragma unroll
    for (int j = 0; j < 4; ++j) {
#pragma unroll
        for (int i = 0; i < 4; ++i)
            y[j][i] = fmaxf(acc[j][i] + bv[i], 0.f);
        float s = y[j][0] + y[j][1] + y[j][2] + y[j][3];
        s += __shfl_xor(s, 1); s += __shfl_xor(s, 2);
        s += __shfl_xor(s, 4); s += __shfl_xor(s, 8);
        float mean = s * (1.f / 64.f);
        float d0 = y[j][0] - mean, d1 = y[j][1] - mean;
        float d2 = y[j][2] - mean, d3 = y[j][3] - mean;
        float q = d0 * d0 + d1 * d1 + d2 * d2 + d3 * d3;
        q += __shfl_xor(q, 1); q += __shfl_xor(q, 2);
        q += __shfl_xor(q, 4); q += __shfl_xor(q, 8);
        float inv = rsqrtf(q * (1.f / 64.f) + LN_EPS);
#pragma unroll
        for (int i = 0; i < 4; ++i)
            y[j][i] = (y[j][i] - mean) * inv * gv[i] + bev[i];
    }
}

// ---------------------------------------------------------------------------
// Fused encoder: enc = LN(relu(feat@W1.T+b1)); out = LN(relu([enc|emb]@W2.T+b2))
// written to z and A. One 64-row block does both GEMMs (K=128 each).
// ---------------------------------------------------------------------------
__global__ __launch_bounds__(256)
void encode_fused_kernel(const float* __restrict__ feat,
                         const float* __restrict__ W1, const float* __restrict__ b1,
                         const float* __restrict__ g1, const float* __restrict__ be1,
                         const float* __restrict__ emb,
                         const float* __restrict__ W2, const float* __restrict__ b2,
                         const float* __restrict__ g2, const float* __restrict__ be2,
                         float* __restrict__ z, float* __restrict__ Aout,
                         int M, int yoff)
{
    constexpr int K = 128, SA = 132, SW = 68;
    __shared__ float As[64 * SA];   // 33.8 KB
    __shared__ float Ws[K * SW];    // 34.8 KB

    const int t = threadIdx.x;
    const int row0 = blockIdx.x * 64;
    const int r0 = 4 * (t >> 4);
    const int n0 = 4 * (t & 15);

    // ---- stage feat tile (float4, coalesced) ----
#pragma unroll
    for (int i = 0; i < 8; ++i) {
        int idx = t + i * 256;           // over 64*32 float4
        int r = idx >> 5, k4 = idx & 31;
        int gr = row0 + r;
        float4 v = make_float4(0.f, 0.f, 0.f, 0.f);
        if (gr < M) v = *(const float4*)&feat[(size_t)gr * K + k4 * 4];
        *(float4*)&As[r * SA + k4 * 4] = v;
    }
    // ---- stage W1 transposed ----
#pragma unroll
    for (int i = 0; i < 32; ++i) {
        int e = t + i * 256;             // over 64*128
        int n = e >> 7, k = e & 127;
        Ws[k * SW + n] = W1[e];
    }
    __syncthreads();

    float acc[4][4] = {};
    gemm_tile<K, SA, SW>(As, Ws, r0, n0, acc);
    float y[4][4];
    relu_ln(acc, y, b1, g1, be1, n0);
    __syncthreads();   // all reads of As/Ws done

    // ---- phase B staging: As = [enc | emb], Ws = W2^T ----
#pragma unroll
    for (int j = 0; j < 4; ++j)
        *(float4*)&As[(r0 + j) * SA + n0] = make_float4(y[j][0], y[j][1], y[j][2], y[j][3]);
#pragma unroll
    for (int i = 0; i < 4; ++i) {
        int idx = t + i * 256;           // over 64*16 float4
        int r = idx >> 4, c4 = idx & 15;
        int gr = row0 + r;
        float4 v = make_float4(0.f, 0.f, 0.f, 0.f);
        if (gr < M) v = *(const float4*)&emb[(size_t)gr * HH + c4 * 4];
        *(float4*)&As[r * SA + 64 + c4 * 4] = v;
    }
#pragma unroll
    for (int i = 0; i < 32; ++i) {
        int e = t + i * 256;
        int n = e >> 7, k = e & 127;
        Ws[k * SW + n] = W2[e];
    }
    __syncthreads();

    float acc2[4][4] = {};
    gemm_tile<K, SA, SW>(As, Ws, r0, n0, acc2);
    float y2[4][4];
    relu_ln(acc2, y2, b2, g2, be2, n0);

#pragma unroll
    for (int j = 0; j < 4; ++j) {
        int gr = row0 + r0 + j;
        if (gr < M) {
            float4 v = make_float4(y2[j][0], y2[j][1], y2[j][2], y2[j][3]);
            *(float4*)&z[(size_t)(yoff + gr) * HH + n0] = v;
            *(float4*)&Aout[(size_t)(yoff + gr) * HH + n0] = v;
        }
    }
}

// ---------------------------------------------------------------------------
// Plain vectorized linear (gcn): Y = X@W.T + b, K=64, no activation.
// ---------------------------------------------------------------------------
__global__ __launch_bounds__(256)
void linear64_kernel(const float* __restrict__ X, const float* __restrict__ W,
                     const float* __restrict__ bias, float* __restrict__ Y, int M)
{
    constexpr int K = 64, SA = 68, SW = 68;
    __shared__ float As[64 * SA];
    __shared__ float Ws[K * SW];

    const int t = threadIdx.x;
    const int row0 = blockIdx.x * 64;
    const int r0 = 4 * (t >> 4);
    const int n0 = 4 * (t & 15);

#pragma unroll
    for (int i = 0; i < 4; ++i) {
        int idx = t + i * 256;           // over 64*16 float4
        int r = idx >> 4, k4 = idx & 15;
        int gr = row0 + r;
        float4 v = make_float4(0.f, 0.f, 0.f, 0.f);
        if (gr < M) v = *(const float4*)&X[(size_t)gr * K + k4 * 4];
        *(float4*)&As[r * SA + k4 * 4] = v;
    }
#pragma unroll
    for (int i = 0; i < 16; ++i) {
        int e = t + i * 256;             // over 64*64
        int n = e >> 6, k = e & 63;
        Ws[k * SW + n] = W[e];
    }
    __syncthreads();

    float acc[4][4] = {};
    gemm_tile<K, SA, SW>(As, Ws, r0, n0, acc);

    float bv[4] = { bias[n0], bias[n0 + 1], bias[n0 + 2], bias[n0 + 3] };
#pragma unroll
    for (int j = 0; j < 4; ++j) {
        int gr = row0 + r0 + j;
        if (gr < M) {
            float4 v = make_float4(acc[j][0] + bv[0], acc[j][1] + bv[1],
                                   acc[j][2] + bv[2], acc[j][3] + bv[3]);
            *(float4*)&Y[(size_t)gr * HH + n0] = v;
        }
    }
}

// ---------------------------------------------------------------------------
// CSR build
// ---------------------------------------------------------------------------
__global__ __launch_bounds__(256)
void zero_int_kernel(int* __restrict__ p, int n)
{
    for (int i = blockIdx.x * 256 + threadIdx.x; i < n; i += gridDim.x * 256)
        p[i] = 0;
}

__global__ __launch_bounds__(256)
void hist_kernel(const int* __restrict__ rows, int* __restrict__ counts)
{
    int e = blockIdx.x * 256 + threadIdx.x;
    if (e < NEDGES) atomicAdd(&counts[rows[e]], 1);
}

__global__ __launch_bounds__(256)
void scan_blocks_kernel(const int* __restrict__ counts, int* __restrict__ ex,
                        int* __restrict__ bsum)
{
    __shared__ int wtot[4];
    int t = threadIdx.x;
    int base = blockIdx.x * 1024 + t * 4;
    int v0 = 0, v1 = 0, v2 = 0, v3 = 0;
    if (base + 3 < N_NODES) {
        int4 c = *reinterpret_cast<const int4*>(&counts[base]);
        v0 = c.x; v1 = c.y; v2 = c.z; v3 = c.w;
    } else {
        if (base + 0 < N_NODES) v0 = counts[base + 0];
        if (base + 1 < N_NODES) v1 = counts[base + 1];
        if (base + 2 < N_NODES) v2 = counts[base + 2];
        if (base + 3 < N_NODES) v3 = counts[base + 3];
    }
    int s1 = v0 + v1, s2 = s1 + v2, tot = s2 + v3;
    int inc = tot;
#pragma unroll
    for (int d = 1; d < 64; d <<= 1) {
        int u = __shfl_up(inc, d);
        if ((t & 63) >= d) inc += u;
    }
    if ((t & 63) == 63) wtot[t >> 6] = inc;
    __syncthreads();
    int w = t >> 6;
    int woff = 0;
#pragma unroll
    for (int i = 0; i < 4; ++i)
        if (i < w) woff += wtot[i];
    int ex0 = woff + inc - tot;
    if (base + 0 < N_NODES) ex[base + 0] = ex0;
    if (base + 1 < N_NODES) ex[base + 1] = ex0 + v0;
    if (base + 2 < N_NODES) ex[base + 2] = ex0 + s1;
    if (base + 3 < N_NODES) ex[base + 3] = ex0 + s2;
    if (t == 255) bsum[blockIdx.x] = woff + inc;
}

__global__ __launch_bounds__(256)
void scan_small_kernel(int* __restrict__ bsum, int nb)
{
    __shared__ int wtot[4];
    int t = threadIdx.x;
    int v = (t < nb) ? bsum[t] : 0;
    int inc = v;
#pragma unroll
    for (int d = 1; d < 64; d <<= 1) {
        int u = __shfl_up(inc, d);
        if ((t & 63) >= d) inc += u;
    }
    if ((t & 63) == 63) wtot[t >> 6] = inc;
    __syncthreads();
    int w = t >> 6;
    int woff = 0;
#pragma unroll
    for (int i = 0; i < 4; ++i)
        if (i < w) woff += wtot[i];
    if (t < nb) bsum[t] = woff + inc - v;
}

__global__ __launch_bounds__(256)
void finalize_kernel(int* __restrict__ row_ptr, const int* __restrict__ bsum,
                     int* __restrict__ cursor)
{
    int i = blockIdx.x * 256 + threadIdx.x;
    if (i < N_NODES) {
        int v = row_ptr[i] + bsum[i >> 10];
        row_ptr[i] = v;
        cursor[i] = v;
    }
    if (i == 0) row_ptr[N_NODES] = NEDGES;
}

__global__ __launch_bounds__(256)
void scatter_kernel(const int* __restrict__ rows, const int* __restrict__ cols,
                    const float* __restrict__ vals, int* __restrict__ cursor,
                    int* __restrict__ csr_col, float* __restrict__ csr_val)
{
    int e = blockIdx.x * 256 + threadIdx.x;
    if (e < NEDGES) {
        int r = rows[e];
        int p = atomicAdd(&cursor[r], 1);
        csr_col[p] = cols[e];
        csr_val[p] = vals[e];
    }
}

// ---------------------------------------------------------------------------
// CSR SPMM: 16 lanes per row (float4 over H=64), fused relu + z-accumulate.
// ---------------------------------------------------------------------------
__global__ __launch_bounds__(256)
void spmm_csr_kernel(const int* __restrict__ row_ptr, const int* __restrict__ csr_col,
                     const float* __restrict__ csr_val, const float* __restrict__ Xin,
                     float* __restrict__ A, float* __restrict__ z,
                     int dorelu, int writeA)
{
    int t = threadIdx.x;
    int r = blockIdx.x * 16 + (t >> 4);
    if (r >= N_NODES) return;
    int q = (t & 15) * 4;
    int e = row_ptr[r], end = row_ptr[r + 1];
    float4 acc = make_float4(0.f, 0.f, 0.f, 0.f);
    for (; e + 1 < end; e += 2) {
        int c0 = csr_col[e], c1 = csr_col[e + 1];
        float v0 = csr_val[e], v1 = csr_val[e + 1];
        float4 x0 = *reinterpret_cast<const float4*>(&Xin[(size_t)c0 * HH + q]);
        float4 x1 = *reinterpret_cast<const float4*>(&Xin[(size_t)c1 * HH + q]);
        acc.x += v0 * x0.x; acc.y += v0 * x0.y; acc.z += v0 * x0.z; acc.w += v0 * x0.w;
        acc.x += v1 * x1.x; acc.y += v1 * x1.y; acc.z += v1 * x1.z; acc.w += v1 * x1.w;
    }
    if (e < end) {
        int c = csr_col[e];
        float v = csr_val[e];
        float4 x = *reinterpret_cast<const float4*>(&Xin[(size_t)c * HH + q]);
        acc.x += v * x.x; acc.y += v * x.y; acc.z += v * x.z; acc.w += v * x.w;
    }
    if (dorelu) {
        acc.x = fmaxf(acc.x, 0.f); acc.y = fmaxf(acc.y, 0.f);
        acc.z = fmaxf(acc.z, 0.f); acc.w = fmaxf(acc.w, 0.f);
    }
    size_t o = (size_t)r * HH + q;
    if (writeA) *reinterpret_cast<float4*>(&A[o]) = acc;
    float4 zz = *reinterpret_cast<float4*>(&z[o]);
    zz.x += acc.x; zz.y += acc.y; zz.z += acc.z; zz.w += acc.w;
    *reinterpret_cast<float4*>(&z[o]) = zz;
}

// ---------------------------------------------------------------------------
// Scorer (K=256 GEMM, vectorized LDS)
// ---------------------------------------------------------------------------
__global__ __launch_bounds__(256)
void scorer_kernel(const float* __restrict__ z, const int* __restrict__ uidx,
                   const int* __restrict__ iidx,
                   const float* __restrict__ s1W, const float* __restrict__ s1b,
                   const float* __restrict__ s2W, const float* __restrict__ s2b,
                   const float* __restrict__ ubias, const float* __restrict__ ibias,
                   const float* __restrict__ gmean, float* __restrict__ out)
{
    constexpr int K = 256, SA = 268, SW = 68;
    __shared__ float As[64 * SA];   // 68.6 KB
    __shared__ float Ws[K * SW];    // 69.6 KB

    const int t = threadIdx.x;
    const int row0 = blockIdx.x * 64;
    const int r0 = 4 * (t >> 4);
    const int n0 = 4 * (t & 15);

    // stage zu | zi (scaled by 1/3), float4 gathers
#pragma unroll
    for (int i = 0; i < 8; ++i) {
        int idx = t + i * 256;           // over 2*64*16 float4
        int half = idx >> 10;
        int rid = idx & 1023;
        int r = rid >> 4, c4 = rid & 15;
        int q = row0 + r;
        int node = half ? (N_USERS + iidx[q]) : uidx[q];
        float4 v = *(const float4*)&z[(size_t)node * HH + c4 * 4];
        v.x *= (1.f / 3.f); v.y *= (1.f / 3.f); v.z *= (1.f / 3.f); v.w *= (1.f / 3.f);
        *(float4*)&As[r * SA + half * 64 + c4 * 4] = v;
    }
    // stage s1W transposed
#pragma unroll
    for (int i = 0; i < 64; ++i) {
        int e = t + i * 256;
        int n = e >> 8, k = e & 255;
        Ws[k * SW + n] = s1W[e];
    }
    __syncthreads();
    // products: zu*zi and |zu-zi|
#pragma unroll
    for (int i = 0; i < 4; ++i) {
        int idx = t + i * 256;           // over 64*16 float4
        int r = idx >> 4, c4 = idx & 15;
        float4 a = *(const float4*)&As[r * SA + c4 * 4];
        float4 b = *(const float4*)&As[r * SA + 64 + c4 * 4];
        float4 p, d;
        p.x = a.x * b.x; p.y = a.y * b.y; p.z = a.z * b.z; p.w = a.w * b.w;
        d.x = fabsf(a.x - b.x); d.y = fabsf(a.y - b.y);
        d.z = fabsf(a.z - b.z); d.w = fabsf(a.w - b.w);
        *(float4*)&As[r * SA + 128 + c4 * 4] = p;
        *(float4*)&As[r * SA + 192 + c4 * 4] = d;
    }
    __syncthreads();

    float acc[4][4] = {};
    gemm_tile<K, SA, SW>(As, Ws, r0, n0, acc);

    float b1[4]  = { s1b[n0], s1b[n0 + 1], s1b[n0 + 2], s1b[n0 + 3] };
    float s2w[4] = { s2W[n0], s2W[n0 + 1], s2W[n0 + 2], s2W[n0 + 3] };
    float pj[4];
#pragma unroll
    for (int j = 0; j < 4; ++j) {
        float p = 0.f;
#pragma unroll
        for (int i = 0; i < 4; ++i)
            p += fmaxf(acc[j][i] + b1[i], 0.f) * s2w[i];
        p += __shfl_xor(p, 1); p += __shfl_xor(p, 2);
        p += __shfl_xor(p, 4); p += __shfl_xor(p, 8);
        pj[j] = p;
    }
    if ((t & 15) == 0) {
        float gm = gmean[0], b2 = s2b[0];
#pragma unroll
        for (int j = 0; j < 4; ++j) {
            int q = row0 + r0 + j;
            float pred = gm + ubias[uidx[q]] + ibias[iidx[q]] + b2 + pj[j];
            pred = fminf(fmaxf(pred, 1.f), 5.f);
            out[q] = pred;
        }
    }
}

// ---------------------------------------------------------------------------
extern "C" void kernel_launch(void* const* d_in, const int* in_sizes, int n_in,
                              void* d_out, int out_size, void* d_ws, size_t ws_size,
                              hipStream_t stream)
{
    const float* user_feat = (const float*)d_in[0];
    const float* item_feat = (const float*)d_in[1];
    const float* adj_vals  = (const float*)d_in[2];
    const float* ue_W  = (const float*)d_in[3];
    const float* ue_b  = (const float*)d_in[4];
    const float* ue_g  = (const float*)d_in[5];
    const float* ue_be = (const float*)d_in[6];
    const float* ie_W  = (const float*)d_in[7];
    const float* ie_b  = (const float*)d_in[8];
    const float* ie_g  = (const float*)d_in[9];
    const float* ie_be = (const float*)d_in[10];
    const float* uid_emb = (const float*)d_in[11];
    const float* iid_emb = (const float*)d_in[12];
    const float* uf_W  = (const float*)d_in[13];
    const float* uf_b  = (const float*)d_in[14];
    const float* uf_g  = (const float*)d_in[15];
    const float* uf_be = (const float*)d_in[16];
    const float* if_W  = (const float*)d_in[17];
    const float* if_b  = (const float*)d_in[18];
    const float* if_g  = (const float*)d_in[19];
    const float* if_be = (const float*)d_in[20];
    const float* gcn_W = (const float*)d_in[21];
    const float* gcn_b = (const float*)d_in[22];
    const float* ubias = (const float*)d_in[23];
    const float* ibias = (const float*)d_in[24];
    const float* s1_W  = (const float*)d_in[25];
    const float* s1_b  = (const float*)d_in[26];
    const float* s2_W  = (const float*)d_in[27];
    const float* s2_b  = (const float*)d_in[28];
    const float* gmean = (const float*)d_in[29];
    const int* adj_rows = (const int*)d_in[30];
    const int* adj_cols = (const int*)d_in[31];
    const int* user_idx = (const int*)d_in[32];
    const int* item_idx = (const int*)d_in[33];
    float* out = (float*)d_out;

    float* z = (float*)d_ws;                       // [N*64]
    float* A = z + (size_t)N_NODES * HH;           // [N*64]
    float* B = A + (size_t)N_NODES * HH;           // [N*64]
    float* csr_val = B + (size_t)N_NODES * HH;     // [E]
    int* csr_col = (int*)(csr_val + NEDGES);       // [E]
    int* row_ptr = csr_col + NEDGES;               // [N+1]
    int* cursor  = row_ptr + N_NODES + 4;          // [N]
    int* bsum    = cursor + N_NODES;               // [SCAN_NBLK]

    const int ublocks = (N_USERS + 63) / 64;
    const int iblocks = (N_ITEMS + 63) / 64;
    const int nblocks = (N_NODES + 63) / 64;
    const int eblocks = (NEDGES + 255) / 256;

    // ---- CSR build ----
    zero_int_kernel<<<512, 256, 0, stream>>>(cursor, N_NODES);
    hist_kernel<<<eblocks, 256, 0, stream>>>(adj_rows, cursor);
    scan_blocks_kernel<<<SCAN_NBLK, 256, 0, stream>>>(cursor, row_ptr, bsum);
    scan_small_kernel<<<1, 256, 0, stream>>>(bsum, SCAN_NBLK);
    finalize_kernel<<<(N_NODES + 255) / 256, 256, 0, stream>>>(row_ptr, bsum, cursor);
    scatter_kernel<<<eblocks, 256, 0, stream>>>(adj_rows, adj_cols, adj_vals,
                                                cursor, csr_col, csr_val);

    // ---- fused encoders: feat->enc->fusion -> z (=x0) and A (=x) ----
    encode_fused_kernel<<<ublocks, 256, 0, stream>>>(
        user_feat, ue_W, ue_b, ue_g, ue_be, uid_emb,
        uf_W, uf_b, uf_g, uf_be, z, A, N_USERS, 0);
    encode_fused_kernel<<<iblocks, 256, 0, stream>>>(
        item_feat, ie_W, ie_b, ie_g, ie_be, iid_emb,
        if_W, if_b, if_g, if_be, z, A, N_ITEMS, N_USERS);

    // ---- GCN layers ----
    const int sblocks = (N_NODES * 16 + 255) / 256;
    for (int l = 0; l < 2; ++l) {
        linear64_kernel<<<nblocks, 256, 0, stream>>>(
            A, gcn_W + l * HH * HH, gcn_b + l * HH, B, N_NODES);
        spmm_csr_kernel<<<sblocks, 256, 0, stream>>>(
            row_ptr, csr_col, csr_val, B, A, z,
            /*dorelu=*/l == 0 ? 1 : 0, /*writeA=*/l == 0 ? 1 : 0);
    }

    // ---- scorer ----
    scorer_kernel<<<NQ / 64, 256, 0, stream>>>(
        z, user_idx, item_idx, s1_W, s1_b, s2_W, s2_b, ubias, ibias, gmean, out);
}

// Round 5
// 563.106 us; speedup vs baseline: 4.7013x; 1.0774x over previous
//
#include <hip/hip_runtime.h>

#define N_USERS 100000
#define N_ITEMS 50000
#define N_NODES 150000
#define HH 64
#define NEDGES 1200000
#define NQ 16384
#define LN_EPS 1e-5f
#define SCAN_NBLK 147   // ceil(150000/1024)

// ---------------------------------------------------------------------------
// GEMM tile: 64 rows x 64 cols, 256 threads, 4x4 per thread, K=64 chunk.
// As[64][SA], Ws[64][SW] (W transposed: Ws[k][n]). All reads ds_read_b128.
// ---------------------------------------------------------------------------
template<int SA, int SW>
__device__ __forceinline__ void gemm_tile64(const float* __restrict__ As,
                                            const float* __restrict__ Ws,
                                            int r0, int n0, float acc[4][4])
{
#pragma unroll 2
    for (int k0 = 0; k0 < 64; k0 += 4) {
        float4 a[4], w[4];
        a[0] = *(const float4*)&As[(r0 + 0) * SA + k0];
        a[1] = *(const float4*)&As[(r0 + 1) * SA + k0];
        a[2] = *(const float4*)&As[(r0 + 2) * SA + k0];
        a[3] = *(const float4*)&As[(r0 + 3) * SA + k0];
        w[0] = *(const float4*)&Ws[(k0 + 0) * SW + n0];
        w[1] = *(const float4*)&Ws[(k0 + 1) * SW + n0];
        w[2] = *(const float4*)&Ws[(k0 + 2) * SW + n0];
        w[3] = *(const float4*)&Ws[(k0 + 3) * SW + n0];
#pragma unroll
        for (int j = 0; j < 4; ++j) {
            float av[4] = { a[j].x, a[j].y, a[j].z, a[j].w };
#pragma unroll
            for (int kk = 0; kk < 4; ++kk) {
                acc[j][0] += av[kk] * (&w[kk].x)[0];
                acc[j][1] += av[kk] * (&w[kk].x)[1];
                acc[j][2] += av[kk] * (&w[kk].x)[2];
                acc[j][3] += av[kk] * (&w[kk].x)[3];
            }
        }
    }
}

// bias+ReLU+LayerNorm epilogue (row's 64 cols live in 16 contiguous lanes)
__device__ __forceinline__ void relu_ln(float acc[4][4], float y[4][4],
                                        const float* __restrict__ bias,
                                        const float* __restrict__ g,
                                        const float* __restrict__ be, int n0)
{
    float bv[4] = { bias[n0], bias[n0 + 1], bias[n0 + 2], bias[n0 + 3] };
    float gv[4] = { g[n0], g[n0 + 1], g[n0 + 2], g[n0 + 3] };
    float bev[4] = { be[n0], be[n0 + 1], be[n0 + 2], be[n0 + 3] };
#pragma unroll
    for (int j = 0; j < 4; ++j) {
#pragma unroll
        for (int i = 0; i < 4; ++i)
            y[j][i] = fmaxf(acc[j][i] + bv[i], 0.f);
        float s = y[j][0] + y[j][1] + y[j][2] + y[j][3];
        s += __shfl_xor(s, 1); s += __shfl_xor(s, 2);
        s += __shfl_xor(s, 4); s += __shfl_xor(s, 8);
        float mean = s * (1.f / 64.f);
        float d0 = y[j][0] - mean, d1 = y[j][1] - mean;
        float d2 = y[j][2] - mean, d3 = y[j][3] - mean;
        float q = d0 * d0 + d1 * d1 + d2 * d2 + d3 * d3;
        q += __shfl_xor(q, 1); q += __shfl_xor(q, 2);
        q += __shfl_xor(q, 4); q += __shfl_xor(q, 8);
        float inv = rsqrtf(q * (1.f / 64.f) + LN_EPS);
#pragma unroll
        for (int i = 0; i < 4; ++i)
            y[j][i] = (y[j][i] - mean) * inv * gv[i] + bev[i];
    }
}

// ---------------------------------------------------------------------------
// Merged fused encoder (users + items in one grid).
// enc = LN(relu(feat@W1.T+b1)); out = LN(relu([enc|emb]@W2.T+b2)) -> z, A.
// K=128 GEMMs done in 2 chunks of 64; LDS = 34.8KB -> 4 blocks/CU.
// ---------------------------------------------------------------------------
__global__ __launch_bounds__(256)
void encode_fused_kernel(int ublocks,
                         const float* __restrict__ ufeat, const float* __restrict__ ifeat,
                         const float* __restrict__ uW1, const float* __restrict__ iW1,
                         const float* __restrict__ ub1, const float* __restrict__ ib1,
                         const float* __restrict__ ug1, const float* __restrict__ ig1,
                         const float* __restrict__ ube1, const float* __restrict__ ibe1,
                         const float* __restrict__ uemb, const float* __restrict__ iemb,
                         const float* __restrict__ uW2, const float* __restrict__ iW2,
                         const float* __restrict__ ub2, const float* __restrict__ ib2,
                         const float* __restrict__ ug2, const float* __restrict__ ig2,
                         const float* __restrict__ ube2, const float* __restrict__ ibe2,
                         float* __restrict__ z, float* __restrict__ Aout)
{
    constexpr int SA = 68, SW = 68;
    __shared__ float As[64 * SA];   // 17.4 KB
    __shared__ float Ws[64 * SW];   // 17.4 KB

    const int bid = blockIdx.x;
    const bool isU = bid < ublocks;
    const float* feat = isU ? ufeat : ifeat;
    const float* W1 = isU ? uW1 : iW1;
    const float* b1 = isU ? ub1 : ib1;
    const float* g1 = isU ? ug1 : ig1;
    const float* be1 = isU ? ube1 : ibe1;
    const float* emb = isU ? uemb : iemb;
    const float* W2 = isU ? uW2 : iW2;
    const float* b2 = isU ? ub2 : ib2;
    const float* g2 = isU ? ug2 : ig2;
    const float* be2 = isU ? ube2 : ibe2;
    const int M = isU ? N_USERS : N_ITEMS;
    const int yoff = isU ? 0 : N_USERS;
    const int row0 = (isU ? bid : bid - ublocks) * 64;

    const int t = threadIdx.x;
    const int r0 = 4 * (t >> 4);
    const int n0 = 4 * (t & 15);

    float acc[4][4] = {};
    // ---- phase A: feat @ W1.T, 2 K-chunks ----
#pragma unroll
    for (int c = 0; c < 2; ++c) {
#pragma unroll
        for (int i = 0; i < 4; ++i) {
            int idx = t + i * 256;           // 64 rows x 16 float4
            int r = idx >> 4, k4 = idx & 15;
            int gr = row0 + r;
            float4 v = make_float4(0.f, 0.f, 0.f, 0.f);
            if (gr < M) v = *(const float4*)&feat[(size_t)gr * 128 + c * 64 + k4 * 4];
            *(float4*)&As[r * SA + k4 * 4] = v;
        }
#pragma unroll
        for (int i = 0; i < 16; ++i) {
            int e = t + i * 256;             // 64 n x 64 k
            int n = e >> 6, k = e & 63;
            Ws[k * SW + n] = W1[n * 128 + c * 64 + k];
        }
        __syncthreads();
        gemm_tile64<SA, SW>(As, Ws, r0, n0, acc);
        __syncthreads();
    }
    float y[4][4];
    relu_ln(acc, y, b1, g1, be1, n0);

    // ---- phase B chunk 0: As = enc, W2[:, 0:64] ----
#pragma unroll
    for (int j = 0; j < 4; ++j)
        *(float4*)&As[(r0 + j) * SA + n0] = make_float4(y[j][0], y[j][1], y[j][2], y[j][3]);
#pragma unroll
    for (int i = 0; i < 16; ++i) {
        int e = t + i * 256;
        int n = e >> 6, k = e & 63;
        Ws[k * SW + n] = W2[n * 128 + k];
    }
    __syncthreads();
    float acc2[4][4] = {};
    gemm_tile64<SA, SW>(As, Ws, r0, n0, acc2);
    __syncthreads();
    // ---- phase B chunk 1: As = emb, W2[:, 64:128] ----
#pragma unroll
    for (int i = 0; i < 4; ++i) {
        int idx = t + i * 256;
        int r = idx >> 4, k4 = idx & 15;
        int gr = row0 + r;
        float4 v = make_float4(0.f, 0.f, 0.f, 0.f);
        if (gr < M) v = *(const float4*)&emb[(size_t)gr * 64 + k4 * 4];
        *(float4*)&As[r * SA + k4 * 4] = v;
    }
#pragma unroll
    for (int i = 0; i < 16; ++i) {
        int e = t + i * 256;
        int n = e >> 6, k = e & 63;
        Ws[k * SW + n] = W2[n * 128 + 64 + k];
    }
    __syncthreads();
    gemm_tile64<SA, SW>(As, Ws, r0, n0, acc2);
    float y2[4][4];
    relu_ln(acc2, y2, b2, g2, be2, n0);

#pragma unroll
    for (int j = 0; j < 4; ++j) {
        int gr = row0 + r0 + j;
        if (gr < M) {
            float4 v = make_float4(y2[j][0], y2[j][1], y2[j][2], y2[j][3]);
            *(float4*)&z[(size_t)(yoff + gr) * HH + n0] = v;
            *(float4*)&Aout[(size_t)(yoff + gr) * HH + n0] = v;
        }
    }
}

// ---------------------------------------------------------------------------
// GCN linear: Y = X@W.T + b, K=64. LDS 34.8KB -> 4 blocks/CU.
// ---------------------------------------------------------------------------
__global__ __launch_bounds__(256)
void linear64_kernel(const float* __restrict__ X, const float* __restrict__ W,
                     const float* __restrict__ bias, float* __restrict__ Y, int M)
{
    constexpr int SA = 68, SW = 68;
    __shared__ float As[64 * SA];
    __shared__ float Ws[64 * SW];

    const int t = threadIdx.x;
    const int row0 = blockIdx.x * 64;
    const int r0 = 4 * (t >> 4);
    const int n0 = 4 * (t & 15);

#pragma unroll
    for (int i = 0; i < 4; ++i) {
        int idx = t + i * 256;
        int r = idx >> 4, k4 = idx & 15;
        int gr = row0 + r;
        float4 v = make_float4(0.f, 0.f, 0.f, 0.f);
        if (gr < M) v = *(const float4*)&X[(size_t)gr * HH + k4 * 4];
        *(float4*)&As[r * SA + k4 * 4] = v;
    }
#pragma unroll
    for (int i = 0; i < 16; ++i) {
        int e = t + i * 256;
        int n = e >> 6, k = e & 63;
        Ws[k * SW + n] = W[n * HH + k];
    }
    __syncthreads();

    float acc[4][4] = {};
    gemm_tile64<SA, SW>(As, Ws, r0, n0, acc);

    float bv[4] = { bias[n0], bias[n0 + 1], bias[n0 + 2], bias[n0 + 3] };
#pragma unroll
    for (int j = 0; j < 4; ++j) {
        int gr = row0 + r0 + j;
        if (gr < M) {
            float4 v = make_float4(acc[j][0] + bv[0], acc[j][1] + bv[1],
                                   acc[j][2] + bv[2], acc[j][3] + bv[3]);
            *(float4*)&Y[(size_t)gr * HH + n0] = v;
        }
    }
}

// ---------------------------------------------------------------------------
// CSR build
// ---------------------------------------------------------------------------
__global__ __launch_bounds__(256)
void zero_int_kernel(int* __restrict__ p, int n)
{
    for (int i = blockIdx.x * 256 + threadIdx.x; i < n; i += gridDim.x * 256)
        p[i] = 0;
}

__global__ __launch_bounds__(256)
void hist_kernel(const int* __restrict__ rows, int* __restrict__ counts)
{
    int e = blockIdx.x * 256 + threadIdx.x;
    if (e < NEDGES) atomicAdd(&counts[rows[e]], 1);
}

__global__ __launch_bounds__(256)
void scan_blocks_kernel(const int* __restrict__ counts, int* __restrict__ ex,
                        int* __restrict__ bsum)
{
    __shared__ int wtot[4];
    int t = threadIdx.x;
    int base = blockIdx.x * 1024 + t * 4;
    int v0 = 0, v1 = 0, v2 = 0, v3 = 0;
    if (base + 3 < N_NODES) {
        int4 c = *reinterpret_cast<const int4*>(&counts[base]);
        v0 = c.x; v1 = c.y; v2 = c.z; v3 = c.w;
    } else {
        if (base + 0 < N_NODES) v0 = counts[base + 0];
        if (base + 1 < N_NODES) v1 = counts[base + 1];
        if (base + 2 < N_NODES) v2 = counts[base + 2];
        if (base + 3 < N_NODES) v3 = counts[base + 3];
    }
    int s1 = v0 + v1, s2 = s1 + v2, tot = s2 + v3;
    int inc = tot;
#pragma unroll
    for (int d = 1; d < 64; d <<= 1) {
        int u = __shfl_up(inc, d);
        if ((t & 63) >= d) inc += u;
    }
    if ((t & 63) == 63) wtot[t >> 6] = inc;
    __syncthreads();
    int w = t >> 6;
    int woff = 0;
#pragma unroll
    for (int i = 0; i < 4; ++i)
        if (i < w) woff += wtot[i];
    int ex0 = woff + inc - tot;
    if (base + 0 < N_NODES) ex[base + 0] = ex0;
    if (base + 1 < N_NODES) ex[base + 1] = ex0 + v0;
    if (base + 2 < N_NODES) ex[base + 2] = ex0 + s1;
    if (base + 3 < N_NODES) ex[base + 3] = ex0 + s2;
    if (t == 255) bsum[blockIdx.x] = woff + inc;
}

__global__ __launch_bounds__(256)
void scan_small_kernel(int* __restrict__ bsum, int nb)
{
    __shared__ int wtot[4];
    int t = threadIdx.x;
    int v = (t < nb) ? bsum[t] : 0;
    int inc = v;
#pragma unroll
    for (int d = 1; d < 64; d <<= 1) {
        int u = __shfl_up(inc, d);
        if ((t & 63) >= d) inc += u;
    }
    if ((t & 63) == 63) wtot[t >> 6] = inc;
    __syncthreads();
    int w = t >> 6;
    int woff = 0;
#pragma unroll
    for (int i = 0; i < 4; ++i)
        if (i < w) woff += wtot[i];
    if (t < nb) bsum[t] = woff + inc - v;
}

__global__ __launch_bounds__(256)
void finalize_kernel(int* __restrict__ row_ptr, const int* __restrict__ bsum,
                     int* __restrict__ cursor)
{
    int i = blockIdx.x * 256 + threadIdx.x;
    if (i < N_NODES) {
        int v = row_ptr[i] + bsum[i >> 10];
        row_ptr[i] = v;
        cursor[i] = v;
    }
    if (i == 0) row_ptr[N_NODES] = NEDGES;
}

__global__ __launch_bounds__(256)
void scatter_kernel(const int* __restrict__ rows, const int* __restrict__ cols,
                    const float* __restrict__ vals, int* __restrict__ cursor,
                    int* __restrict__ csr_col, float* __restrict__ csr_val)
{
    int e = blockIdx.x * 256 + threadIdx.x;
    if (e < NEDGES) {
        int r = rows[e];
        int p = atomicAdd(&cursor[r], 1);
        csr_col[p] = cols[e];
        csr_val[p] = vals[e];
    }
}

// ---------------------------------------------------------------------------
// CSR SPMM: 16 lanes per row (float4 over H=64), fused relu + z-accumulate.
// Unroll 4: four independent gather chains in flight.
// ---------------------------------------------------------------------------
__global__ __launch_bounds__(256)
void spmm_csr_kernel(const int* __restrict__ row_ptr, const int* __restrict__ csr_col,
                     const float* __restrict__ csr_val, const float* __restrict__ Xin,
                     float* __restrict__ A, float* __restrict__ z,
                     int dorelu, int writeA)
{
    int t = threadIdx.x;
    int r = blockIdx.x * 16 + (t >> 4);
    if (r >= N_NODES) return;
    int q = (t & 15) * 4;
    int e = row_ptr[r], end = row_ptr[r + 1];
    float4 acc = make_float4(0.f, 0.f, 0.f, 0.f);
    for (; e + 3 < end; e += 4) {
        int c0 = csr_col[e + 0], c1 = csr_col[e + 1];
        int c2 = csr_col[e + 2], c3 = csr_col[e + 3];
        float v0 = csr_val[e + 0], v1 = csr_val[e + 1];
        float v2 = csr_val[e + 2], v3 = csr_val[e + 3];
        float4 x0 = *reinterpret_cast<const float4*>(&Xin[(size_t)c0 * HH + q]);
        float4 x1 = *reinterpret_cast<const float4*>(&Xin[(size_t)c1 * HH + q]);
        float4 x2 = *reinterpret_cast<const float4*>(&Xin[(size_t)c2 * HH + q]);
        float4 x3 = *reinterpret_cast<const float4*>(&Xin[(size_t)c3 * HH + q]);
        acc.x += v0 * x0.x; acc.y += v0 * x0.y; acc.z += v0 * x0.z; acc.w += v0 * x0.w;
        acc.x += v1 * x1.x; acc.y += v1 * x1.y; acc.z += v1 * x1.z; acc.w += v1 * x1.w;
        acc.x += v2 * x2.x; acc.y += v2 * x2.y; acc.z += v2 * x2.z; acc.w += v2 * x2.w;
        acc.x += v3 * x3.x; acc.y += v3 * x3.y; acc.z += v3 * x3.z; acc.w += v3 * x3.w;
    }
    for (; e < end; ++e) {
        int c = csr_col[e];
        float v = csr_val[e];
        float4 x = *reinterpret_cast<const float4*>(&Xin[(size_t)c * HH + q]);
        acc.x += v * x.x; acc.y += v * x.y; acc.z += v * x.z; acc.w += v * x.w;
    }
    if (dorelu) {
        acc.x = fmaxf(acc.x, 0.f); acc.y = fmaxf(acc.y, 0.f);
        acc.z = fmaxf(acc.z, 0.f); acc.w = fmaxf(acc.w, 0.f);
    }
    size_t o = (size_t)r * HH + q;
    if (writeA) *reinterpret_cast<float4*>(&A[o]) = acc;
    float4 zz = *reinterpret_cast<float4*>(&z[o]);
    zz.x += acc.x; zz.y += acc.y; zz.z += acc.z; zz.w += acc.w;
    *reinterpret_cast<float4*>(&z[o]) = zz;
}

// ---------------------------------------------------------------------------
// Scorer: 32 queries per block, K=256 GEMM in 4 chunks of 64.
// LDS = 51.7KB -> 3 blocks/CU. 2x4 tile per thread.
// ---------------------------------------------------------------------------
__global__ __launch_bounds__(256)
void scorer_kernel(const float* __restrict__ z, const int* __restrict__ uidx,
                   const int* __restrict__ iidx,
                   const float* __restrict__ s1W, const float* __restrict__ s1b,
                   const float* __restrict__ s2W, const float* __restrict__ s2b,
                   const float* __restrict__ ubias, const float* __restrict__ ibias,
                   const float* __restrict__ gmean, float* __restrict__ out)
{
    constexpr int SA = 268, SW = 68;
    __shared__ float As[32 * SA];   // 34.3 KB
    __shared__ float Ws[64 * SW];   // 17.4 KB

    const int t = threadIdx.x;
    const int row0 = blockIdx.x * 32;
    const int r0 = 2 * (t >> 4);
    const int n0 = 4 * (t & 15);

    // stage zu | zi (x 1/3): 32 rows x 2 halves x 16 float4
#pragma unroll
    for (int i = 0; i < 4; ++i) {
        int idx = t + i * 256;
        int half = idx >> 9;
        int rid = idx & 511;
        int r = rid >> 4, c4 = rid & 15;
        int q = row0 + r;
        int node = half ? (N_USERS + iidx[q]) : uidx[q];
        float4 v = *(const float4*)&z[(size_t)node * HH + c4 * 4];
        v.x *= (1.f / 3.f); v.y *= (1.f / 3.f); v.z *= (1.f / 3.f); v.w *= (1.f / 3.f);
        *(float4*)&As[r * SA + half * 64 + c4 * 4] = v;
    }
    __syncthreads();
    // products zu*zi, |zu-zi|
#pragma unroll
    for (int i = 0; i < 2; ++i) {
        int idx = t + i * 256;
        int r = idx >> 4, c4 = idx & 15;
        float4 a = *(const float4*)&As[r * SA + c4 * 4];
        float4 b = *(const float4*)&As[r * SA + 64 + c4 * 4];
        float4 p, d;
        p.x = a.x * b.x; p.y = a.y * b.y; p.z = a.z * b.z; p.w = a.w * b.w;
        d.x = fabsf(a.x - b.x); d.y = fabsf(a.y - b.y);
        d.z = fabsf(a.z - b.z); d.w = fabsf(a.w - b.w);
        *(float4*)&As[r * SA + 128 + c4 * 4] = p;
        *(float4*)&As[r * SA + 192 + c4 * 4] = d;
    }
    __syncthreads();

    float acc[2][4] = {};
#pragma unroll
    for (int c = 0; c < 4; ++c) {
#pragma unroll
        for (int i = 0; i < 16; ++i) {
            int e = t + i * 256;
            int n = e >> 6, k = e & 63;
            Ws[k * SW + n] = s1W[n * 256 + c * 64 + k];
        }
        __syncthreads();
#pragma unroll 2
        for (int k0 = 0; k0 < 64; k0 += 4) {
            float4 a0 = *(const float4*)&As[(r0 + 0) * SA + c * 64 + k0];
            float4 a1 = *(const float4*)&As[(r0 + 1) * SA + c * 64 + k0];
            float4 w[4];
            w[0] = *(const float4*)&Ws[(k0 + 0) * SW + n0];
            w[1] = *(const float4*)&Ws[(k0 + 1) * SW + n0];
            w[2] = *(const float4*)&Ws[(k0 + 2) * SW + n0];
            w[3] = *(const float4*)&Ws[(k0 + 3) * SW + n0];
            float av0[4] = { a0.x, a0.y, a0.z, a0.w };
            float av1[4] = { a1.x, a1.y, a1.z, a1.w };
#pragma unroll
            for (int kk = 0; kk < 4; ++kk) {
                acc[0][0] += av0[kk] * (&w[kk].x)[0];
                acc[0][1] += av0[kk] * (&w[kk].x)[1];
                acc[0][2] += av0[kk] * (&w[kk].x)[2];
                acc[0][3] += av0[kk] * (&w[kk].x)[3];
                acc[1][0] += av1[kk] * (&w[kk].x)[0];
                acc[1][1] += av1[kk] * (&w[kk].x)[1];
                acc[1][2] += av1[kk] * (&w[kk].x)[2];
                acc[1][3] += av1[kk] * (&w[kk].x)[3];
            }
        }
        __syncthreads();
    }

    float b1v[4] = { s1b[n0], s1b[n0 + 1], s1b[n0 + 2], s1b[n0 + 3] };
    float s2w[4] = { s2W[n0], s2W[n0 + 1], s2W[n0 + 2], s2W[n0 + 3] };
    float pj[2];
#pragma unroll
    for (int j = 0; j < 2; ++j) {
        float p = 0.f;
#pragma unroll
        for (int i = 0; i < 4; ++i)
            p += fmaxf(acc[j][i] + b1v[i], 0.f) * s2w[i];
        p += __shfl_xor(p, 1); p += __shfl_xor(p, 2);
        p += __shfl_xor(p, 4); p += __shfl_xor(p, 8);
        pj[j] = p;
    }
    if ((t & 15) == 0) {
        float gm = gmean[0], b2 = s2b[0];
#pragma unroll
        for (int j = 0; j < 2; ++j) {
            int q = row0 + r0 + j;
            float pred = gm + ubias[uidx[q]] + ibias[iidx[q]] + b2 + pj[j];
            pred = fminf(fmaxf(pred, 1.f), 5.f);
            out[q] = pred;
        }
    }
}

// ---------------------------------------------------------------------------
extern "C" void kernel_launch(void* const* d_in, const int* in_sizes, int n_in,
                              void* d_out, int out_size, void* d_ws, size_t ws_size,
                              hipStream_t stream)
{
    const float* user_feat = (const float*)d_in[0];
    const float* item_feat = (const float*)d_in[1];
    const float* adj_vals  = (const float*)d_in[2];
    const float* ue_W  = (const float*)d_in[3];
    const float* ue_b  = (const float*)d_in[4];
    const float* ue_g  = (const float*)d_in[5];
    const float* ue_be = (const float*)d_in[6];
    const float* ie_W  = (const float*)d_in[7];
    const float* ie_b  = (const float*)d_in[8];
    const float* ie_g  = (const float*)d_in[9];
    const float* ie_be = (const float*)d_in[10];
    const float* uid_emb = (const float*)d_in[11];
    const float* iid_emb = (const float*)d_in[12];
    const float* uf_W  = (const float*)d_in[13];
    const float* uf_b  = (const float*)d_in[14];
    const float* uf_g  = (const float*)d_in[15];
    const float* uf_be = (const float*)d_in[16];
    const float* if_W  = (const float*)d_in[17];
    const float* if_b  = (const float*)d_in[18];
    const float* if_g  = (const float*)d_in[19];
    const float* if_be = (const float*)d_in[20];
    const float* gcn_W = (const float*)d_in[21];
    const float* gcn_b = (const float*)d_in[22];
    const float* ubias = (const float*)d_in[23];
    const float* ibias = (const float*)d_in[24];
    const float* s1_W  = (const float*)d_in[25];
    const float* s1_b  = (const float*)d_in[26];
    const float* s2_W  = (const float*)d_in[27];
    const float* s2_b  = (const float*)d_in[28];
    const float* gmean = (const float*)d_in[29];
    const int* adj_rows = (const int*)d_in[30];
    const int* adj_cols = (const int*)d_in[31];
    const int* user_idx = (const int*)d_in[32];
    const int* item_idx = (const int*)d_in[33];
    float* out = (float*)d_out;

    float* z = (float*)d_ws;                       // [N*64]
    float* A = z + (size_t)N_NODES * HH;           // [N*64]
    float* B = A + (size_t)N_NODES * HH;           // [N*64]
    float* csr_val = B + (size_t)N_NODES * HH;     // [E]
    int* csr_col = (int*)(csr_val + NEDGES);       // [E]
    int* row_ptr = csr_col + NEDGES;               // [N+1]
    int* cursor  = row_ptr + N_NODES + 4;          // [N]
    int* bsum    = cursor + N_NODES;               // [SCAN_NBLK]

    const int ublocks = (N_USERS + 63) / 64;       // 1563
    const int iblocks = (N_ITEMS + 63) / 64;       // 782
    const int nblocks = (N_NODES + 63) / 64;       // 2344
    const int eblocks = (NEDGES + 255) / 256;

    // ---- CSR build ----
    zero_int_kernel<<<512, 256, 0, stream>>>(cursor, N_NODES);
    hist_kernel<<<eblocks, 256, 0, stream>>>(adj_rows, cursor);
    scan_blocks_kernel<<<SCAN_NBLK, 256, 0, stream>>>(cursor, row_ptr, bsum);
    scan_small_kernel<<<1, 256, 0, stream>>>(bsum, SCAN_NBLK);
    finalize_kernel<<<(N_NODES + 255) / 256, 256, 0, stream>>>(row_ptr, bsum, cursor);
    scatter_kernel<<<eblocks, 256, 0, stream>>>(adj_rows, adj_cols, adj_vals,
                                                cursor, csr_col, csr_val);

    // ---- merged fused encoders -> z (=x0) and A (=x) ----
    encode_fused_kernel<<<ublocks + iblocks, 256, 0, stream>>>(
        ublocks,
        user_feat, item_feat, ue_W, ie_W, ue_b, ie_b, ue_g, ie_g, ue_be, ie_be,
        uid_emb, iid_emb, uf_W, if_W, uf_b, if_b, uf_g, if_g, uf_be, if_be,
        z, A);

    // ---- GCN layers ----
    const int sblocks = (N_NODES * 16 + 255) / 256;
    for (int l = 0; l < 2; ++l) {
        linear64_kernel<<<nblocks, 256, 0, stream>>>(
            A, gcn_W + l * HH * HH, gcn_b + l * HH, B, N_NODES);
        spmm_csr_kernel<<<sblocks, 256, 0, stream>>>(
            row_ptr, csr_col, csr_val, B, A, z,
            /*dorelu=*/l == 0 ? 1 : 0, /*writeA=*/l == 0 ? 1 : 0);
    }

    // ---- scorer ----
    scorer_kernel<<<NQ / 32, 256, 0, stream>>>(
        z, user_idx, item_idx, s1_W, s1_b, s2_W, s2_b, ubias, ibias, gmean, out);
}